// Round 15
// baseline (356.626 us; speedup 1.0000x reference)
//
#include <hip/hip_runtime.h>

// FDTD rollout — SINGLE fused kernel (cooperative, flag-synced groups),
// R14 instruction diet + TS=8 (halved vertical halo -> 25% fewer step
// instructions; region 48 rows x 64 cols per 32x32 tile, redundancy 3x
// instead of 4x). 31 cheap flag-sync boundaries instead of 15.
// Geometry: region row = 6*w + j (j<6); physical row 0 = region row 8
// (by==0, w==1, j==2); physical row 511 = region row 39 (by==15, w==6, j==3).
// Valid-at-group-end set: rows [8,40) x lanes [8,56); stores: rows [8,40)
// x lanes [16,48) (the 32x32 tile).

#define HH 512
#define WW 512
#define HW (HH * WW)
#define TILE 32
#define TS 8
#define NW 8      // waves per block
#define RPT 6     // rows per thread (48-row region)
#define PHC ((float)(2.0 * 3.1415926 * 100.0))

#define LDS_BARRIER() asm volatile("s_waitcnt lgkmcnt(0)\n\ts_barrier" ::: "memory")

#if __has_builtin(__builtin_amdgcn_update_dpp)
__device__ __forceinline__ float nbrL(float x) {   // value from lane-1 (left)
    int i = __builtin_bit_cast(int, x);
    i = __builtin_amdgcn_update_dpp(i, i, 0x138, 0xf, 0xf, false); // wave_shr:1
    return __builtin_bit_cast(float, i);
}
__device__ __forceinline__ float nbrR(float x) {   // value from lane+1 (right)
    int i = __builtin_bit_cast(int, x);
    i = __builtin_amdgcn_update_dpp(i, i, 0x130, 0xf, 0xf, false); // wave_shl:1
    return __builtin_bit_cast(float, i);
}
#else
__device__ __forceinline__ float nbrL(float x) { return __shfl_up(x, 1, 64); }
__device__ __forceinline__ float nbrR(float x) { return __shfl_down(x, 1, 64); }
#endif

__global__ void fdtd_zero_flags(int* f) { f[threadIdx.x] = 0; }

// One step: reads cur=X (+halo via sbR), prev=Y; writes new frame into Y.
template<bool COLEDGE>
__device__ __forceinline__ void fstep(
    float (&X)[RPT], float (&Y)[RPT],
    const float (&rr)[RPT], const float (&dcv)[RPT],
    const float (*sbR)[2][64], float (*sbW)[2][64],
    int lane, int w, int wup, int sup, int wdn, int sdn,
    bool topw, bool botw, bool isC0, bool isC511,
    bool whs, unsigned smask, const float (&srcT)[260], int n,
    bool lstore, int jlo, int jhi, float* op)
{
    const float upb = sbR[wup][sup][lane];
    const float dnb = sbR[wdn][sdn][lane];
    #pragma unroll
    for (int j = 0; j < RPT; ++j) {
        const float c = X[j];
        const float u = (j == 0)       ? upb : X[j - 1];
        const float d = (j == RPT - 1) ? dnb : X[j + 1];
        const float lft = nbrL(c);
        const float rgt = nbrR(c);
        Y[j] = 2.f * c - Y[j] + rr[j] * (((u + d) + (lft + rgt)) - 4.f * c);
    }
    if (whs) {                       // only waves containing a source cell
        const float srcv = srcT[n];
        #pragma unroll
        for (int j = 0; j < RPT; ++j)
            if ((smask >> j) & 1u) Y[j] = srcv;
    }
    // precedence (last wins): row0 < col0 < col511 < row511
    if (topw) Y[2] = X[2] - dcv[2] * (X[2] - X[3]);        // physical row 0
    if (COLEDGE) {
        #pragma unroll
        for (int j = 0; j < RPT; ++j) {
            const float c   = X[j];
            const float rgt = nbrR(c);
            const float lft = nbrL(c);
            float v = Y[j];
            v = isC0   ? (c - dcv[j] * (c - rgt)) : v;
            v = isC511 ? (c - dcv[j] * (c - lft)) : v;
            Y[j] = v;
        }
    }
    if (botw) Y[3] = X[3] - dcv[3] * (X[3] - X[2]);        // physical row 511
    sbW[w][0][lane] = Y[0];
    sbW[w][1][lane] = Y[RPT - 1];
    if (lstore) {
        for (int j = jlo; j < jhi; ++j)
            __hip_atomic_store(op + j * WW, Y[j], __ATOMIC_RELAXED,
                               __HIP_MEMORY_SCOPE_AGENT);
    }
    LDS_BARRIER();
}

__global__ __launch_bounds__(512)
void fdtd_ts8(const float* __restrict__ in_out,
              const float* __restrict__ cmap,
              const int* __restrict__ locx,
              const int* __restrict__ locy,
              const int* __restrict__ pb,
              const int* __restrict__ pid2,
              float* __restrict__ out,
              int steps, int* __restrict__ flags)
{
    __shared__ float sb[2][NW][2][64];   // [buf][wave][top/bottom row][col]
    __shared__ float srcT[260];          // source value per global step n

    const int tid  = threadIdx.x;
    const int lane = tid & 63;
    const int w    = tid >> 6;
    const int bx   = blockIdx.x & 15;
    const int by   = blockIdx.x >> 4;
    const int gx0  = bx * TILE - 16;     // horizontal halo stays 16 (64 lanes)
    const int gy0  = by * TILE - TS;     // vertical halo 8 -> 48-row region
    const int gc   = gx0 + lane;
    const int R    = w * RPT;            // region row base (0..42)

    const int lx0 = locx[0], ly0 = locy[0];
    const int lx1 = locx[1], ly1 = locy[1];
    const int lx2 = locx[2], ly2 = locy[2];
    const int Bn  = pb[0] * pid2[0];

    if (tid <= steps && tid < 260)
        srcT[tid] = 1500.0f * __sinf(PHC * (float)(Bn + tid + 1) * 1.0e-4f);

    float A[RPT], B[RPT], rr[RPT], dcv[RPT];
    unsigned smask = 0;
    const bool colOK = (gc >= 0) & (gc < WW);

    #pragma unroll
    for (int j = 0; j < RPT; ++j) {
        const int gr = gy0 + R + j;
        float c = 0.f, ce = 0.f, pp = 0.f;
        if (colOK && gr >= 0 && gr < HH) {
            const int gi = gr * WW + gc;
            c  = cmap[gi];
            ce = in_out[(size_t)HW + gi];  // frame 1 (cur)
            pp = in_out[gi];               // frame 0 (prev)
        }
        A[j] = ce; B[j] = pp;
        rr[j]  = 1.0e-8f * c * c;
        dcv[j] = 1.0e-4f * c;
        if ((gr == lx0 && gc == ly0) || (gr == lx1 && gc == ly1) ||
            (gr == lx2 && gc == ly2)) smask |= (1u << j);
    }
    const bool whs     = __any((int)(smask != 0));
    const bool topw    = (by == 0)  && (w == 1);   // region row 8 = grid row 0
    const bool botw    = (by == 15) && (w == 6);   // region row 39 = row 511
    const bool coledge = (bx == 0) || (bx == 15);
    const bool isC0    = (gc == 0);
    const bool isC511  = (gc == WW - 1);
    // store set: rows [8,40) x lanes [16,48)  (wave-uniform j-interval)
    const int  jlo     = max(0, 8 - R);
    const int  jhi     = min(RPT, 40 - R);
    const bool lstore  = (lane >= 16) & (lane < 48) & (jlo < jhi);
    // keep-valid set: rows [8,40) x lanes [8,56)
    const bool vlane   = (lane >= 8) & (lane < 56);
    const int  rowOff  = (gy0 + R) * WW + gc;

    const int wup = (w == 0)      ? 0      : w - 1;
    const int sup = (w == 0)      ? 0      : 1;
    const int wdn = (w == NW - 1) ? NW - 1 : w + 1;
    const int sdn = (w == NW - 1) ? 1      : 0;

    sb[0][w][0][lane] = A[0];
    sb[0][w][1][lane] = A[RPT - 1];
    __syncthreads();

    for (int t0 = 0; t0 < steps; t0 += TS) {
        const int nk = (steps - t0 < TS) ? (steps - t0) : TS;

        if (t0 > 0) {
            // ---- group boundary: inter-block neighbor-flag sync ----
            asm volatile("s_waitcnt vmcnt(0)" ::: "memory");
            __syncthreads();
            if (tid == 0)
                __hip_atomic_store(&flags[blockIdx.x], t0,
                                   __ATOMIC_RELAXED, __HIP_MEMORY_SCOPE_AGENT);
            if (tid < 8) {
                const int dy[8] = {-1,-1,-1, 0, 0, 1, 1, 1};
                const int dx[8] = {-1, 0, 1,-1, 1,-1, 0, 1};
                const int nby = by + dy[tid];
                const int nbx = bx + dx[tid];
                if (nby >= 0 && nby < 16 && nbx >= 0 && nbx < 16) {
                    const int nb = (nby << 4) | nbx;
                    while (__hip_atomic_load(&flags[nb], __ATOMIC_RELAXED,
                                             __HIP_MEMORY_SCOPE_AGENT) < t0)
                        __builtin_amdgcn_s_sleep(2);
                }
            }
            __syncthreads();
            // reload rows not in the keep-valid set
            const float* cF = out + (size_t)(t0 - 1) * (size_t)HW;
            const float* pF = cF - HW;
            #pragma unroll
            for (int j = 0; j < RPT; ++j) {
                const bool vrow = (R + j >= 8) & (R + j < 40);
                if (!(vrow & vlane)) {
                    const int gr = gy0 + R + j;
                    float ce = 0.f, pp = 0.f;
                    if (colOK && gr >= 0 && gr < HH) {
                        const int gi = gr * WW + gc;
                        ce = __hip_atomic_load(cF + gi, __ATOMIC_RELAXED,
                                               __HIP_MEMORY_SCOPE_AGENT);
                        pp = __hip_atomic_load(pF + gi, __ATOMIC_RELAXED,
                                               __HIP_MEMORY_SCOPE_AGENT);
                    }
                    A[j] = ce; B[j] = pp;
                }
            }
            sb[0][w][0][lane] = A[0];
            sb[0][w][1][lane] = A[RPT - 1];
            __syncthreads();
        }

        float* op = out + (size_t)t0 * (size_t)HW + rowOff;
        if (!coledge) {
            for (int k = 1; k + 1 <= nk; k += 2) {
                fstep<false>(A, B, rr, dcv, sb[0], sb[1], lane, w, wup, sup,
                             wdn, sdn, topw, botw, isC0, isC511, whs, smask,
                             srcT, t0 + k, lstore, jlo, jhi, op);
                op += HW;
                fstep<false>(B, A, rr, dcv, sb[1], sb[0], lane, w, wup, sup,
                             wdn, sdn, topw, botw, isC0, isC511, whs, smask,
                             srcT, t0 + k + 1, lstore, jlo, jhi, op);
                op += HW;
            }
            if (nk & 1) {
                fstep<false>(A, B, rr, dcv, sb[0], sb[1], lane, w, wup, sup,
                             wdn, sdn, topw, botw, isC0, isC511, whs, smask,
                             srcT, t0 + nk, lstore, jlo, jhi, op);
                #pragma unroll
                for (int j = 0; j < RPT; ++j) {
                    const float t = A[j]; A[j] = B[j]; B[j] = t;
                }
            }
        } else {
            for (int k = 1; k + 1 <= nk; k += 2) {
                fstep<true>(A, B, rr, dcv, sb[0], sb[1], lane, w, wup, sup,
                            wdn, sdn, topw, botw, isC0, isC511, whs, smask,
                            srcT, t0 + k, lstore, jlo, jhi, op);
                op += HW;
                fstep<true>(B, A, rr, dcv, sb[1], sb[0], lane, w, wup, sup,
                            wdn, sdn, topw, botw, isC0, isC511, whs, smask,
                            srcT, t0 + k + 1, lstore, jlo, jhi, op);
                op += HW;
            }
            if (nk & 1) {
                fstep<true>(A, B, rr, dcv, sb[0], sb[1], lane, w, wup, sup,
                            wdn, sdn, topw, botw, isC0, isC511, whs, smask,
                            srcT, t0 + nk, lstore, jlo, jhi, op);
                #pragma unroll
                for (int j = 0; j < RPT; ++j) {
                    const float t = A[j]; A[j] = B[j]; B[j] = t;
                }
            }
        }
    }
}

extern "C" void kernel_launch(void* const* d_in, const int* in_sizes, int n_in,
                              void* d_out, int out_size, void* d_ws, size_t ws_size,
                              hipStream_t stream) {
    const float* in_out = (const float*)d_in[0];   // [steps+2, 1, 512, 512]
    const float* cmap   = (const float*)d_in[1];   // [1,1,512,512]
    const int*   locx   = (const int*)d_in[2];
    const int*   locy   = (const int*)d_in[3];
    const int*   pb     = (const int*)d_in[4];     // bsize1
    const int*   pid2   = (const int*)d_in[5];     // id2
    float*       outp   = (float*)d_out;
    int*         flags  = (int*)d_ws;              // 256 progress flags

    int steps = out_size / HW;

    hipLaunchKernelGGL(fdtd_zero_flags, dim3(1), dim3(256), 0, stream, flags);

    void* args[] = { (void*)&in_out, (void*)&cmap, (void*)&locx, (void*)&locy,
                     (void*)&pb, (void*)&pid2, (void*)&outp, (void*)&steps,
                     (void*)&flags };
    hipLaunchCooperativeKernel((const void*)fdtd_ts8,
                               dim3((HH / TILE) * (WW / TILE)),  // 256 blocks
                               dim3(512), args, 0, stream);
}